// Round 1
// baseline (778.552 us; speedup 1.0000x reference)
//
#include <hip/hip_runtime.h>

// Segmented block-diagonal equivariant linear (e3nn-style).
// x: [131072, 832] fp32, segments (mul,d): (128,1)@0, (128,3)@128, (64,5)@512.
// out[n, off + v*d + i] = alpha * sum_u x[n, off + u*d + i] * W[u,v], alpha=1/sqrt(mul).
//
// Strategy: memory-bound (872 MB traffic ~ 138us floor). Compute via bf16 MFMA
// (16x16x32) so compute (~10us) hides entirely under memory. Weights are
// prepacked (bf16, alpha folded, fragment-ordered) into d_ws by a tiny kernel.

typedef __bf16 bf16x8 __attribute__((ext_vector_type(8)));
typedef float  f32x4  __attribute__((ext_vector_type(4)));

#define NROWS 131072
#define ROWF  832

static __device__ __forceinline__ unsigned short f2bf(float f) {
    unsigned u = __builtin_bit_cast(unsigned, f);
    u += 0x7fffu + ((u >> 16) & 1u);          // round-to-nearest-even
    return (unsigned short)(u >> 16);
}

// Pack layout per segment: [KT][VT][64 lanes][8 elems] bf16.
// B fragment for mfma_f32_16x16x32_bf16: lane l holds B[k][j], j = l&15,
// k = (l>>4)*8 + e  (8 contiguous k per lane).
__global__ void prepack_kernel(const float* __restrict__ W0,
                               const float* __restrict__ W1,
                               const float* __restrict__ W2,
                               unsigned short* __restrict__ bp)
{
    int idx = blockIdx.x * 256 + threadIdx.x;
    if (idx >= 36864) return;                  // 16384 + 16384 + 4096
    const float* W; int mul, base; float alpha;
    if (idx < 16384)      { W = W0; mul = 128; base = 0;     alpha = 0.08838834764831845f; }
    else if (idx < 32768) { W = W1; mul = 128; base = 16384; alpha = 0.08838834764831845f; }
    else                  { W = W2; mul = 64;  base = 32768; alpha = 0.125f; }
    int local = idx - base;
    int e  = local & 7;
    int l  = (local >> 3) & 63;
    int t  = local >> 9;                       // kt*VT + vt
    int VT = mul >> 4;
    int kt = t / VT;
    int vt = t - kt * VT;
    int u  = kt * 32 + ((l >> 4) << 3) + e;
    int v  = vt * 16 + (l & 15);
    bp[idx] = f2bf(W[u * mul + v] * alpha);
}

// One block = 32 rows of x, full segment width. X' view: [(i,n_local), u]
// staged as bf16 LDS planes [i*32+n][u], XOR-swizzled (16B chunk ^= row&7)
// so A-fragment ds_read_b128 is conflict-free (2-way = free).
template<int MUL, int D, int XOFF, int WSOFF>
__global__ __launch_bounds__(256)
void seg_kernel(const float* __restrict__ x,
                const unsigned short* __restrict__ bp,
                float* __restrict__ out)
{
    constexpr int TM    = 32;
    constexpr int SEGW  = MUL * D;        // floats per row in this segment
    constexpr int KT    = MUL / 32;       // K tiles (K=32 per MFMA)
    constexpr int VT    = MUL / 16;       // v tiles
    constexpr int VPW   = VT / 4;         // v tiles per wave (4 waves)
    constexpr int MROWS = TM * D;         // rows of X'
    constexpr int MT    = MROWS / 16;     // m tiles
    constexpr int ROWB  = MUL * 2;        // LDS row bytes
    constexpr int CPR   = SEGW / 4;       // float4 chunks per row
    constexpr int ITER  = (TM * CPR) / 256;

    __shared__ unsigned short xs[MROWS * MUL];
    char* xsb = reinterpret_cast<char*>(xs);

    const int tid  = threadIdx.x;
    const int lane = tid & 63;
    const int w    = tid >> 6;
    const int n0   = blockIdx.x * TM;

    // B fragments (weights, L2-hot), held in registers for the whole block.
    bf16x8 bfrag[VPW][KT];
    #pragma unroll
    for (int vi = 0; vi < VPW; ++vi) {
        const int vt = w * VPW + vi;
        #pragma unroll
        for (int kt = 0; kt < KT; ++kt)
            bfrag[vi][kt] = *reinterpret_cast<const bf16x8*>(
                bp + WSOFF + (((kt * VT + vt) * 64 + lane) << 3));
    }

    // ---- stage x tile -> LDS (fp32 coalesced loads, bf16 de-interleaved) ----
    #pragma unroll
    for (int j = 0; j < ITER; ++j) {
        const int id = j * 256 + tid;
        const int n  = id / CPR;
        const int c  = id - n * CPR;
        const f32x4 v4 = *reinterpret_cast<const f32x4*>(
            x + (n0 + n) * ROWF + XOFF + (c << 2));
        if constexpr (D == 1) {
            // 4 consecutive u land in one swizzled 16B chunk, 8B-aligned.
            const int u = c << 2;
            unsigned long long pk = 0;
            #pragma unroll
            for (int q = 0; q < 4; ++q)
                pk |= (unsigned long long)f2bf(v4[q]) << (16 * q);
            const int addr = n * ROWB + (((u >> 3) ^ (n & 7)) << 4) + ((u & 7) << 1);
            *reinterpret_cast<unsigned long long*>(xsb + addr) = pk;
        } else {
            #pragma unroll
            for (int q = 0; q < 4; ++q) {
                const int p = (c << 2) + q;
                const int u = p / D;
                const int i = p - u * D;
                const int m = i * TM + n;     // (m & 7) == (n & 7) since TM=32
                const int addr = m * ROWB + (((u >> 3) ^ (n & 7)) << 4) + ((u & 7) << 1);
                *reinterpret_cast<unsigned short*>(xsb + addr) = f2bf(v4[q]);
            }
        }
    }
    __syncthreads();

    // ---- MFMA: out'[m][v] = X'[m][u] @ (alpha*W)[u][v] ----
    const int l15 = lane & 15;
    const int kg  = lane >> 4;

    #pragma unroll
    for (int mt = 0; mt < MT; ++mt) {
        const int m = mt * 16 + l15;          // A: lane&15 = M row
        bf16x8 afr[KT];
        #pragma unroll
        for (int kt = 0; kt < KT; ++kt) {
            const int chunk = (kt * 4 + kg) ^ (m & 7);
            afr[kt] = *reinterpret_cast<const bf16x8*>(xsb + m * ROWB + (chunk << 4));
        }
        #pragma unroll
        for (int vi = 0; vi < VPW; ++vi) {
            f32x4 acc = {0.f, 0.f, 0.f, 0.f};
            #pragma unroll
            for (int kt = 0; kt < KT; ++kt)
                acc = __builtin_amdgcn_mfma_f32_16x16x32_bf16(
                          afr[kt], bfrag[vi][kt], acc, 0, 0, 0);
            // D: col v = lane&15, row m = (lane>>4)*4 + r (m89-verified layout)
            const int vcol = (w * VPW + vi) * 16 + l15;
            #pragma unroll
            for (int r = 0; r < 4; ++r) {
                const int mm = mt * 16 + kg * 4 + r;
                const int i  = mm >> 5;       // plane (irrep component)
                const int nl = mm & 31;       // local row
                out[(n0 + nl) * ROWF + XOFF + vcol * D + i] = acc[r];
            }
        }
    }
}

extern "C" void kernel_launch(void* const* d_in, const int* in_sizes, int n_in,
                              void* d_out, int out_size, void* d_ws, size_t ws_size,
                              hipStream_t stream) {
    const float* x  = (const float*)d_in[0];
    const float* W0 = (const float*)d_in[1];
    const float* W1 = (const float*)d_in[2];
    const float* W2 = (const float*)d_in[3];
    float* out = (float*)d_out;
    unsigned short* bp = (unsigned short*)d_ws;   // 73728 bytes used

    prepack_kernel<<<144, 256, 0, stream>>>(W0, W1, W2, bp);

    const int grid = NROWS / 32;                  // 4096
    seg_kernel<128, 1,   0,     0><<<grid, 256, 0, stream>>>(x, bp, out);
    seg_kernel<128, 3, 128, 16384><<<grid, 256, 0, stream>>>(x, bp, out);
    seg_kernel< 64, 5, 512, 32768><<<grid, 256, 0, stream>>>(x, bp, out);
}